// Round 1
// baseline (11567.951 us; speedup 1.0000x reference)
//
#include <hip/hip_runtime.h>
#include <hip/hip_cooperative_groups.h>
#include <cmath>

namespace cg = cooperative_groups;

#define NB 32
#define NS 64
#define NK 5
#define NE 512
#define NH 512
#define C1V 2500
#define C2V 10000
#define CSZ1V 7500
#define CSZ2V 40000
#define G4H 2048

// ---- workspace offsets (floats) ----
#define WS_M    0            // 4*512*512 (Wa^2..Wa^5)
#define WS_PK   1048576      // proj_keys 160*512
#define WS_PHI  1130496      // 160
#define WS_SBUF 1130656      // 160
#define WS_COV  1130816      // 2*160
#define WS_GH0  1131136      // 32*2048
#define WS_GH1  1196672
#define WS_H0S  1262208      // 32*512 each
#define WS_C0S  1278592
#define WS_H1S  1294976
#define WS_C1S  1311360
#define WS_QB   1327744
#define WS_X    1344128      // 2048*512 aligned copy of outs
#define WS_P1   2392704      // 2048*128
#define WS_P2   2654848      // 2048*32
#define WS_SUMS 2720384      // 3*2048: head, tail1, tail2
#define WS_HLT  2726528
#define WS_HC1  2728576
#define WS_HC2  2730624
#define WS_L1P  2732672
#define WS_L2P  2734720      // end 2736768 floats (~10.9 MB)

// ---- d_out offsets (floats) ----
#define O_LP   0
#define O_LOSS 2048
#define O_OUTS 2049
#define O_HF   1050625
#define O_CF   1083393
#define O_ATTN 1116161
#define O_COVF 1126401

__device__ __forceinline__ float sigmf(float x){ return 1.0f/(1.0f + expf(-x)); }

__device__ __forceinline__ float dot512(const float* __restrict__ x, const float* __restrict__ w){
  const float4* x4 = (const float4*)x;
  const float4* w4 = (const float4*)w;
  float a0=0.f,a1=0.f,a2=0.f,a3=0.f;
  #pragma unroll 8
  for (int h=0; h<128; h++){
    float4 xx = x4[h]; float4 ww = w4[h];
    a0 = fmaf(xx.x, ww.x, a0); a1 = fmaf(xx.y, ww.y, a1);
    a2 = fmaf(xx.z, ww.z, a2); a3 = fmaf(xx.w, ww.w, a3);
  }
  return (a0+a1)+(a2+a3);
}

__device__ __forceinline__ void dot512x2(const float* __restrict__ x,
                                         const float* __restrict__ wA,
                                         const float* __restrict__ wB,
                                         float& rA, float& rB){
  const float4* x4=(const float4*)x; const float4* a4=(const float4*)wA; const float4* b4=(const float4*)wB;
  float p0=0.f,p1=0.f,p2=0.f,p3=0.f,q0=0.f,q1=0.f,q2=0.f,q3=0.f;
  #pragma unroll 4
  for (int h=0;h<128;h++){
    float4 xx=x4[h]; float4 aa=a4[h]; float4 bb=b4[h];
    p0=fmaf(xx.x,aa.x,p0); p1=fmaf(xx.y,aa.y,p1); p2=fmaf(xx.z,aa.z,p2); p3=fmaf(xx.w,aa.w,p3);
    q0=fmaf(xx.x,bb.x,q0); q1=fmaf(xx.y,bb.y,q1); q2=fmaf(xx.z,bb.z,q2); q3=fmaf(xx.w,bb.w,q3);
  }
  rA += (p0+p1)+(p2+p3); rB += (q0+q1)+(q2+q3);
}

struct ScanArgs {
  const int* inputs; const int* topics; const float* out0;
  const float* h0in; const float* c0in; const float* mask; const float* cover;
  const float* emb; const float* Uf; const float* Ua; const float* Wa;
  const float* vaw; const float* vab;
  const float* wih0; const float* whh0; const float* bih0; const float* bhh0;
  const float* wih1; const float* whh1; const float* bih1; const float* bhh1;
  float* ws; float* out;
};

// Persistent cooperative kernel: preamble (phi, proj_keys, Wa powers) + 64-step scan.
// grid = 208 blocks x 256 threads. 3 grid syncs per step.
__global__ __launch_bounds__(256) void scan_kernel(ScanArgs a){
  cg::grid_group grid = cg::this_grid();
  const int wg = blockIdx.x, tid = threadIdx.x;
  const int GT = gridDim.x * blockDim.x;
  const int gt = wg*256 + tid;
  float* ws = a.ws;
  float* Mp  = ws + WS_M;
  float* pk  = ws + WS_PK;
  float* phi = ws + WS_PHI;
  float* sbuf= ws + WS_SBUF;
  float* cov = ws + WS_COV;
  float* gh0 = ws + WS_GH0;
  float* gh1 = ws + WS_GH1;
  float* h0s = ws + WS_H0S; float* c0s = ws + WS_C0S;
  float* h1s = ws + WS_H1S; float* c1s = ws + WS_C1S;
  float* qb  = ws + WS_QB;  float* X   = ws + WS_X;

  __shared__ float ls[16*516];   // padded activation tile (16 rows)
  __shared__ float gred[512];
  __shared__ float al_l[16*NK];

  // ---------------- preamble ----------------
  for (int i = gt; i < NB*NH; i += GT){
    h0s[i] = a.h0in[i]; c0s[i] = a.c0in[i];
    h1s[i] = a.h0in[NB*NH + i]; c1s[i] = a.c0in[NB*NH + i];
    qb[i] = a.out0[i];
  }
  for (int i = gt; i < NB*NK; i += GT){ cov[i] = a.cover[i]; sbuf[i] = 0.f; }
  if (gt < NB*NK){
    int b = gt/NK, k = gt%NK;
    float ms = 0.f; for (int s=0;s<NS;s++) ms += a.mask[b*NS+s];
    float acc = 0.f;
    for (int kk=0; kk<NK; kk++){
      const float* te = a.emb + (size_t)a.topics[b*NK+kk]*NE;
      const float* uf = a.Uf + (size_t)k*(NK*NE) + kk*NE;
      for (int e=0;e<NE;e++) acc = fmaf(te[e], uf[e], acc);
    }
    phi[gt] = ms * sigmf(acc);
  }
  for (int d = gt; d < NB*NK*NH; d += GT){
    int p = d >> 9, h = d & 511;
    int b = p/NK, k = p%NK;
    const float* te = a.emb + (size_t)a.topics[b*NK+k]*NE;
    pk[d] = dot512(te, a.Ua + (size_t)h*NE);
  }
  grid.sync();
  // Wa powers: M_r = Wa^(r+2), so that head i uses Wa^(i+1) (i=0 -> Wa itself)
  for (int r=0; r<4; r++){
    const float* Asrc = (r==0) ? a.Wa : Mp + (size_t)(r-1)*NH*NH;
    float* Mo = Mp + (size_t)r*NH*NH;
    for (int d = gt; d < NH*NH; d += GT){
      int row = d >> 9, col = d & 511;
      const float* ar = Asrc + (size_t)row*NH;
      float acc = 0.f;
      for (int k2=0;k2<NH;k2++) acc = fmaf(ar[k2], a.Wa[(size_t)k2*NH + col], acc);
      Mo[d] = acc;
    }
    grid.sync();
  }

  // ---------------- scan ----------------
  for (int t=0; t<NS; t++){
    // ---- Phase A: attention score partials + recurrent gate halves ----
    if (wg < 80){
      int i = wg/16, sub = wg%16;
      int bh = sub >> 3, es = sub & 7;
      int b0 = bh*16, e0 = es*64;
      for (int idx=tid; idx<16*512; idx+=256){ int bl=idx>>9, h=idx&511; ls[bl*516+h] = qb[(size_t)(b0+bl)*NH + h]; }
      __syncthreads();
      const float* Mi = (i==0)? a.Wa : Mp + (size_t)(i-1)*NH*NH;
      int bl = tid & 15;
      float sp = 0.f;
      for (int r=0;r<4;r++){
        int e = e0 + (tid>>4) + r*16;
        float acc = dot512(ls + bl*516, Mi + (size_t)e*NH);
        sp += tanhf(acc + pk[((size_t)(b0+bl)*NK + i)*NH + e]) * a.vaw[e];
      }
      gred[tid] = sp;
      __syncthreads();
      if (tid < 16){
        float s2 = 0.f;
        for (int g=0; g<16; g++) s2 += gred[g*16 + tid];
        atomicAdd(&sbuf[(b0+tid)*NK + i], s2);
      }
    } else {
      int u = wg - 80;
      int layer = u >> 6;
      int v2 = u & 63;
      int bh = v2 >> 5, js = v2 & 31;
      int b0 = bh*16, j0 = js*64;
      const float* hsrc = layer ? h1s : h0s;
      const float* whh = layer ? a.whh1 : a.whh0;
      const float* bi  = layer ? a.bih1 : a.bih0;
      const float* bh2 = layer ? a.bhh1 : a.bhh0;
      float* gh = layer ? gh1 : gh0;
      for (int idx=tid; idx<16*512; idx+=256){ int bl=idx>>9, h=idx&511; ls[bl*516+h] = hsrc[(size_t)(b0+bl)*NH + h]; }
      __syncthreads();
      int bl = tid & 15;
      for (int r=0;r<4;r++){
        int j = j0 + (tid>>4) + r*16;
        float acc = dot512(ls + bl*516, whh + (size_t)j*NH);
        gh[(size_t)(b0+bl)*G4H + j] = acc + bi[j] + bh2[j];
      }
    }
    grid.sync();

    // ---- Phase C: softmax/mt/cov + LSTM0 cell ----
    if (wg < 128){
      int bh = wg >> 6, us = wg & 63;
      int b0 = bh*16, u0 = us*8;
      const float* covold = cov + (t&1)*NB*NK;
      if (tid < 16){
        int b = b0 + tid;
        float sc[NK]; float mx = -1e30f;
        for (int k=0;k<NK;k++){ float s = (sbuf[b*NK+k] + a.vab[0]) * covold[b*NK+k]; sc[k]=s; mx = fmaxf(mx,s); }
        float sum = 0.f;
        for (int k=0;k<NK;k++){ sc[k] = expf(sc[k]-mx); sum += sc[k]; }
        for (int k=0;k<NK;k++) al_l[tid*NK+k] = sc[k]/sum;
        if (us == 0){
          float* covnew = cov + ((t+1)&1)*NB*NK;
          for (int k=0;k<NK;k++){
            float alv = al_l[tid*NK+k];
            float cn = covold[b*NK+k] - alv/phi[b*NK+k];
            covnew[b*NK+k] = cn;
            a.out[O_ATTN + (size_t)(t*NB + b)*NK + k] = alv;
            if (t == NS-1) a.out[O_COVF + b*NK + k] = cn;
          }
        }
      }
      __syncthreads();
      // stage 1: embedding half of x
      for (int idx=tid; idx<16*512; idx+=256){ int bl=idx>>9, h=idx&511;
        ls[bl*516+h] = a.emb[(size_t)a.inputs[(b0+bl)*NS + t]*NE + h]; }
      __syncthreads();
      int bl = tid & 15, rem = tid >> 4;
      int u_l = rem & 7, g0 = rem >> 3;
      int jA = g0*NH + u0 + u_l;
      int jB = (g0+2)*NH + u0 + u_l;
      float accA = 0.f, accB = 0.f;
      dot512x2(ls + bl*516, a.wih0 + (size_t)jA*(2*NE), a.wih0 + (size_t)jB*(2*NE), accA, accB);
      __syncthreads();
      // stage 2: mt half of x
      for (int idx=tid; idx<16*512; idx+=256){ int bl2=idx>>9, e=idx&511;
        float m = 0.f;
        for (int k=0;k<NK;k++) m = fmaf(al_l[bl2*NK+k], a.emb[(size_t)a.topics[(b0+bl2)*NK+k]*NE + e], m);
        ls[bl2*516+e] = m; }
      __syncthreads();
      dot512x2(ls + bl*516, a.wih0 + (size_t)jA*(2*NE) + NE, a.wih0 + (size_t)jB*(2*NE) + NE, accA, accB);
      int b = b0 + bl;
      accA += gh0[(size_t)b*G4H + jA];
      accB += gh0[(size_t)b*G4H + jB];
      gred[g0*128 + u_l*16 + bl] = accA;
      gred[(g0+2)*128 + u_l*16 + bl] = accB;
      __syncthreads();
      if (tid < 128){
        int bl2 = tid & 15, ul2 = tid >> 4;
        float gi = gred[0*128 + ul2*16 + bl2];
        float gf = gred[1*128 + ul2*16 + bl2];
        float gg = gred[2*128 + ul2*16 + bl2];
        float go = gred[3*128 + ul2*16 + bl2];
        int b2 = b0 + bl2, uu = u0 + ul2;
        float cp = c0s[(size_t)b2*NH + uu];
        float cn = sigmf(gf)*cp + sigmf(gi)*tanhf(gg);
        float hn = sigmf(go)*tanhf(cn);
        c0s[(size_t)b2*NH + uu] = cn;
        h0s[(size_t)b2*NH + uu] = hn;
        if (t == NS-1){
          a.out[O_HF + (size_t)(0*NB + b2)*NH + uu] = hn;
          a.out[O_CF + (size_t)(0*NB + b2)*NH + uu] = cn;
        }
      }
    }
    grid.sync();

    // ---- Phase D: LSTM1 cell + outputs ----
    if (wg < 128){
      int bh = wg >> 6, us = wg & 63;
      int b0 = bh*16, u0 = us*8;
      for (int idx=tid; idx<16*512; idx+=256){ int bl=idx>>9, h=idx&511; ls[bl*516+h] = h0s[(size_t)(b0+bl)*NH + h]; }
      __syncthreads();
      int bl = tid & 15, rem = tid >> 4;
      int u_l = rem & 7, g0 = rem >> 3;
      int jA = g0*NH + u0 + u_l;
      int jB = (g0+2)*NH + u0 + u_l;
      float accA = 0.f, accB = 0.f;
      dot512x2(ls + bl*516, a.wih1 + (size_t)jA*NH, a.wih1 + (size_t)jB*NH, accA, accB);
      int b = b0 + bl;
      accA += gh1[(size_t)b*G4H + jA];
      accB += gh1[(size_t)b*G4H + jB];
      gred[g0*128 + u_l*16 + bl] = accA;
      gred[(g0+2)*128 + u_l*16 + bl] = accB;
      __syncthreads();
      if (tid < 128){
        int bl2 = tid & 15, ul2 = tid >> 4;
        float gi = gred[0*128 + ul2*16 + bl2];
        float gf = gred[1*128 + ul2*16 + bl2];
        float gg = gred[2*128 + ul2*16 + bl2];
        float go = gred[3*128 + ul2*16 + bl2];
        int b2 = b0 + bl2, uu = u0 + ul2;
        float cp = c1s[(size_t)b2*NH + uu];
        float cn = sigmf(gf)*cp + sigmf(gi)*tanhf(gg);
        float hn = sigmf(go)*tanhf(cn);
        c1s[(size_t)b2*NH + uu] = cn;
        h1s[(size_t)b2*NH + uu] = hn;
        qb[(size_t)b2*NH + uu] = hn;
        size_t rowoff = (size_t)(t*NB + b2)*NH + uu;
        a.out[O_OUTS + rowoff] = hn;
        X[rowoff] = hn;
        if (t == NS-1){
          a.out[O_HF + (size_t)(1*NB + b2)*NH + uu] = hn;
          a.out[O_CF + (size_t)(1*NB + b2)*NH + uu] = cn;
        }
      }
    } else if (wg == 128){
      if (tid < NB*NK) sbuf[tid] = 0.f;   // reset scores for next step
    }
    grid.sync();
  }
}

// ---- adaptive log-softmax kernels ----

__global__ __launch_bounds__(256) void kproj(const float* __restrict__ X,
                                             const float* __restrict__ t1w1,
                                             const float* __restrict__ t2w1,
                                             float* __restrict__ P1, float* __restrict__ P2){
  __shared__ float xs[16*516];
  int r0 = blockIdx.x*16, tid = threadIdx.x;
  for (int idx=tid; idx<16*512; idx+=256){ int rl=idx>>9, h=idx&511; xs[rl*516+h] = X[(size_t)(r0+rl)*NH + h]; }
  __syncthreads();
  for (int k=0;k<8;k++){
    int d = tid + 256*k; int rl = d & 15, c = d >> 4;
    P1[(size_t)(r0+rl)*128 + c] = dot512(xs + rl*516, t1w1 + (size_t)c*NH);
  }
  for (int k=0;k<2;k++){
    int d = tid + 256*k; int rl = d & 15, c = d >> 4;
    P2[(size_t)(r0+rl)*32 + c] = dot512(xs + rl*516, t2w1 + (size_t)c*NH);
  }
}

// head: sum of exp(logit) per row (logits tiny -> no max subtraction needed) + pick 3 logits
__global__ __launch_bounds__(256) void khead(const float* __restrict__ X,
                                             const float* __restrict__ hw,
                                             const int* __restrict__ tgt,
                                             float* __restrict__ sums,
                                             float* __restrict__ hlt, float* __restrict__ hc1, float* __restrict__ hc2){
  __shared__ float xs[16*516];
  __shared__ float red[256];
  int r0 = blockIdx.x*16, tid = threadIdx.x;
  int c0 = blockIdx.y*251;
  int cend = min(2502, c0+251);
  for (int idx=tid; idx<16*512; idx+=256){ int rl=idx>>9, h=idx&511; xs[rl*516+h] = X[(size_t)(r0+rl)*NH + h]; }
  __syncthreads();
  int b16 = tid & 15, cg = tid >> 4;
  int row = r0 + b16;
  int srow = row >> 5, brow = row & 31;
  int tg = tgt[brow*NS + srow];
  int cap = tg < C1V ? tg : (C1V-1);
  float lsum = 0.f;
  const float4* x4 = (const float4*)(xs + b16*516);
  for (int kk0 = 0; kk0 < 16; kk0 += 8){
    float acc[8];
    const float4* wp[8];
    #pragma unroll
    for (int j=0;j<8;j++){
      acc[j] = 0.f;
      int c = c0 + cg + (kk0+j)*16;
      wp[j] = (const float4*)(hw + (size_t)(c < cend ? c : c0)*NH);
    }
    #pragma unroll 2
    for (int h=0; h<128; h++){
      float4 xx = x4[h];
      #pragma unroll
      for (int j=0;j<8;j++){
        float4 ww = wp[j][h];
        acc[j] = fmaf(xx.x, ww.x, acc[j]); acc[j] = fmaf(xx.y, ww.y, acc[j]);
        acc[j] = fmaf(xx.z, ww.z, acc[j]); acc[j] = fmaf(xx.w, ww.w, acc[j]);
      }
    }
    #pragma unroll
    for (int j=0;j<8;j++){
      int c = c0 + cg + (kk0+j)*16;
      if (c < cend){
        float v = acc[j];
        lsum += __expf(v);
        if (c == cap) hlt[row] = v;
        else if (c == C1V) hc1[row] = v;
        else if (c == C1V+1) hc2[row] = v;
      }
    }
  }
  red[tid] = lsum;
  __syncthreads();
  if (tid < 16){
    float s2 = 0.f;
    for (int g=0; g<16; g++) s2 += red[g*16 + tid];
    atomicAdd(&sums[r0 + tid], s2);
  }
}

__global__ __launch_bounds__(256) void ktail1(const float* __restrict__ P1,
                                              const float* __restrict__ w2t,
                                              const int* __restrict__ tgt,
                                              float* __restrict__ sums, float* __restrict__ l1p){
  __shared__ int rlist[16];
  __shared__ float rsum[16];
  __shared__ int rcnt;
  int r0 = blockIdx.x*16, tid = threadIdx.x;
  if (tid == 0) rcnt = 0;
  __syncthreads();
  if (tid < 16){
    rsum[tid] = 0.f;
    int row = r0 + tid;
    int tg = tgt[(row&31)*NS + (row>>5)];
    if (tg >= C1V && tg < C2V){
      int i = atomicAdd(&rcnt, 1);
      rlist[i] = (tid << 16) | (tg - C1V);
    }
  }
  __syncthreads();
  int m = rcnt;
  if (m == 0) return;
  int rl = tid & 15, cg = tid >> 4;
  if (rl < m){
    int pkd = rlist[rl];
    int lrow = pkd >> 16, tl = pkd & 0xffff;
    int orow = r0 + lrow;
    float4 pr[32];
    const float4* p4 = (const float4*)(P1 + (size_t)orow*128);
    #pragma unroll
    for (int h=0;h<32;h++) pr[h] = p4[h];
    int c0 = blockIdx.y*750, cend = min(CSZ1V, c0+750);
    float lsum = 0.f;
    for (int c = c0 + cg; c < cend; c += 16){
      const float4* w4 = (const float4*)(w2t + (size_t)c*128);
      float a0=0.f,a1=0.f,a2=0.f,a3=0.f;
      #pragma unroll
      for (int h=0;h<32;h++){
        float4 ww = w4[h];
        a0=fmaf(pr[h].x,ww.x,a0); a1=fmaf(pr[h].y,ww.y,a1);
        a2=fmaf(pr[h].z,ww.z,a2); a3=fmaf(pr[h].w,ww.w,a3);
      }
      float v = (a0+a1)+(a2+a3);
      lsum += __expf(v);
      if (c == tl) l1p[orow] = v;
    }
    atomicAdd(&rsum[lrow], lsum);
  }
  __syncthreads();
  if (tid < 16 && rsum[tid] != 0.f) atomicAdd(&sums[2048 + r0 + tid], rsum[tid]);
}

__global__ __launch_bounds__(256) void ktail2(const float* __restrict__ P2,
                                              const float* __restrict__ w2t,
                                              const int* __restrict__ tgt,
                                              float* __restrict__ sums, float* __restrict__ l2p){
  __shared__ int rlist[16];
  __shared__ float rsum[16];
  __shared__ int rcnt;
  int r0 = blockIdx.x*16, tid = threadIdx.x;
  if (tid == 0) rcnt = 0;
  __syncthreads();
  if (tid < 16){
    rsum[tid] = 0.f;
    int row = r0 + tid;
    int tg = tgt[(row&31)*NS + (row>>5)];
    if (tg >= C2V){
      int i = atomicAdd(&rcnt, 1);
      rlist[i] = (tid << 16) | (tg - C2V);
    }
  }
  __syncthreads();
  int m = rcnt;
  if (m == 0) return;
  int rl = tid & 15, cg = tid >> 4;
  if (rl < m){
    int pkd = rlist[rl];
    int lrow = pkd >> 16, tl = pkd & 0xffff;
    int orow = r0 + lrow;
    float4 pr[8];
    const float4* p4 = (const float4*)(P2 + (size_t)orow*32);
    #pragma unroll
    for (int h=0;h<8;h++) pr[h] = p4[h];
    int c0 = blockIdx.y*2500, cend = min(CSZ2V, c0+2500);
    float lsum = 0.f;
    for (int c = c0 + cg; c < cend; c += 16){
      const float4* w4 = (const float4*)(w2t + (size_t)c*32);
      float a0=0.f,a1=0.f,a2=0.f,a3=0.f;
      #pragma unroll
      for (int h=0;h<8;h++){
        float4 ww = w4[h];
        a0=fmaf(pr[h].x,ww.x,a0); a1=fmaf(pr[h].y,ww.y,a1);
        a2=fmaf(pr[h].z,ww.z,a2); a3=fmaf(pr[h].w,ww.w,a3);
      }
      float v = (a0+a1)+(a2+a3);
      lsum += __expf(v);
      if (c == tl) l2p[orow] = v;
    }
    atomicAdd(&rsum[lrow], lsum);
  }
  __syncthreads();
  if (tid < 16 && rsum[tid] != 0.f) atomicAdd(&sums[4096 + r0 + tid], rsum[tid]);
}

__global__ __launch_bounds__(256) void kfinal(const float* __restrict__ sums,
                                              const float* __restrict__ hlt, const float* __restrict__ hc1,
                                              const float* __restrict__ hc2, const float* __restrict__ l1p,
                                              const float* __restrict__ l2p, const int* __restrict__ tgt,
                                              float* __restrict__ out){
  __shared__ float red[256];
  int tid = threadIdx.x;
  float acc = 0.f;
  for (int n = tid; n < 2048; n += 256){
    int s = n >> 5, b = n & 31;
    int tg = tgt[b*NS + s];
    float lsh = logf(sums[n]);
    float v;
    if (tg < C1V) v = hlt[n] - lsh;
    else if (tg < C2V) v = (hc1[n] - lsh) + (l1p[n] - logf(sums[2048+n]));
    else v = (hc2[n] - lsh) + (l2p[n] - logf(sums[4096+n]));
    out[O_LP + n] = v;
    acc += v;
  }
  red[tid] = acc;
  __syncthreads();
  for (int off=128; off>0; off>>=1){ if (tid<off) red[tid] += red[tid+off]; __syncthreads(); }
  if (tid==0) out[O_LOSS] = -red[0] / 2048.0f;
}

extern "C" void kernel_launch(void* const* d_in, const int* in_sizes, int n_in,
                              void* d_out, int out_size, void* d_ws, size_t ws_size,
                              hipStream_t stream){
  (void)in_sizes; (void)n_in; (void)out_size; (void)ws_size;
  ScanArgs sa;
  sa.inputs = (const int*)d_in[0];
  sa.topics = (const int*)d_in[1];
  sa.out0   = (const float*)d_in[2];
  sa.h0in   = (const float*)d_in[3];
  sa.c0in   = (const float*)d_in[4];
  sa.mask   = (const float*)d_in[5];
  sa.cover  = (const float*)d_in[7];
  sa.emb    = (const float*)d_in[8];
  sa.Uf     = (const float*)d_in[9];
  sa.Ua     = (const float*)d_in[10];
  sa.Wa     = (const float*)d_in[11];
  sa.vaw    = (const float*)d_in[12];
  sa.vab    = (const float*)d_in[13];
  sa.wih0   = (const float*)d_in[14];
  sa.whh0   = (const float*)d_in[15];
  sa.bih0   = (const float*)d_in[16];
  sa.bhh0   = (const float*)d_in[17];
  sa.wih1   = (const float*)d_in[18];
  sa.whh1   = (const float*)d_in[19];
  sa.bih1   = (const float*)d_in[20];
  sa.bhh1   = (const float*)d_in[21];
  sa.ws  = (float*)d_ws;
  sa.out = (float*)d_out;

  float* ws = (float*)d_ws;
  const int* target = (const int*)d_in[6];

  hipMemsetAsync(ws + WS_SUMS, 0, 6144*sizeof(float), stream);

  void* args[] = { (void*)&sa };
  hipLaunchCooperativeKernel((void*)scan_kernel, dim3(208), dim3(256), args, 0, stream);

  const float* X = ws + WS_X;
  kproj<<<dim3(128),dim3(256),0,stream>>>(X, (const float*)d_in[23], (const float*)d_in[25],
                                          ws + WS_P1, ws + WS_P2);
  khead<<<dim3(128,10),dim3(256),0,stream>>>(X, (const float*)d_in[22], target,
                                             ws + WS_SUMS, ws + WS_HLT, ws + WS_HC1, ws + WS_HC2);
  ktail1<<<dim3(128,10),dim3(256),0,stream>>>(ws + WS_P1, (const float*)d_in[24], target,
                                              ws + WS_SUMS, ws + WS_L1P);
  ktail2<<<dim3(128,16),dim3(256),0,stream>>>(ws + WS_P2, (const float*)d_in[26], target,
                                              ws + WS_SUMS, ws + WS_L2P);
  kfinal<<<dim3(1),dim3(256),0,stream>>>(ws + WS_SUMS, ws + WS_HLT, ws + WS_HC1, ws + WS_HC2,
                                         ws + WS_L1P, ws + WS_L2P, target, (float*)d_out);
}

// Round 2
// 7101.009 us; speedup vs baseline: 1.6291x; 1.6291x over previous
//
#include <hip/hip_runtime.h>
#include <hip/hip_cooperative_groups.h>
#include <cmath>

namespace cg = cooperative_groups;

typedef __attribute__((ext_vector_type(8))) short short8;
typedef __attribute__((ext_vector_type(4))) float f32x4;

#define NB 32
#define NS 64
#define NK 5
#define NE 512
#define NH 512
#define C1V 2500
#define C2V 10000
#define CSZ1V 7500
#define CSZ2V 40000

// ---- workspace BYTE offsets ----
#define PWR_B   0u          // 4*512*512 f32 = 4MB (preamble only; aliased by ghE)
#define GHE_B   0u          // 64*2048*32 bf16 = 8MB
#define QB_B    8388608u    // 32*512 bf16
#define H1B_B   8421376u
#define H0B_B   8454144u
#define SBUF_B  8486912u    // 2*160 f32
#define PHI_B   8488192u    // 160 f32
#define P1_B    8488832u    // 2048*128 f32
#define P2_B    9537408u    // 2048*32 f32
#define SUMS_B  9799552u    // 3*2048 f32
#define HLT_B   9824128u
#define HC1_B   9832320u
#define HC2_B   9840512u
#define L1P_B   9848704u
#define L2P_B   9856896u    // end 9,865,088 bytes (< proven 10.9MB)

// ---- d_out float offsets (verified round-0) ----
#define O_LP   0
#define O_LOSS 2048
#define O_OUTS 2049
#define O_HF   1050625
#define O_CF   1083393
#define O_ATTN 1116161
#define O_COVF 1126401

// ---- LDS byte offsets ----
#define ROWB 1040           // 520 bf16 per padded row (512 data + 8 pad)
#define L_W1  0             // whh1 16 rows bf16
#define L_WI  16640         // wih1
#define L_W0  33280         // whh0
#define L_ACT 49920         // 32 rows bf16
#define L_TP  83200         // 5*16*32 f32
#define L_GH1 93440         // 16*32 f32
#define L_GH0 95488
#define L_GB  97536
#define L_AL  99584         // 32*5 f32
#define LDS_BYTES 100352
// attention wg aliases
#define A_MI  0
#define A_ACT 33280
#define A_SCR 66560         // 64 f32
// ghE staging (preamble, lstm wgs): rows64 at [0,66560), wihE at [66560,83200)

__device__ __forceinline__ float sigmf(float x){ return 1.0f/(1.0f + expf(-x)); }

__device__ __forceinline__ unsigned short f2b16(float f){
  unsigned u = __float_as_uint(f);
  return (unsigned short)((u + 0x7fffu + ((u>>16)&1u)) >> 16);
}
__device__ __forceinline__ float b2f16(unsigned short s){ return __uint_as_float(((unsigned)s)<<16); }

// D[m][n] += A[m][k]*B[n][k] over K=512, one 16x16 tile, rows padded ROWB.
// A rows indexed m=lane&15, B rows indexed n=lane&15; acc[r] -> row (lane>>4)*4+r, col lane&15.
__device__ __forceinline__ f32x4 chain16(const char* Abase, const char* Bbase, int lane){
  f32x4 acc = {0.f,0.f,0.f,0.f};
  int lr = lane & 15, lq = lane >> 4;
  const char* ap = Abase + lr*ROWB + lq*16;
  const char* bp = Bbase + lr*ROWB + lq*16;
  #pragma unroll
  for (int ks=0; ks<16; ks++){
    short8 af = *(const short8*)(ap + ks*64);
    short8 bf = *(const short8*)(bp + ks*64);
    acc = __builtin_amdgcn_mfma_f32_16x16x32_bf16(af, bf, acc, 0, 0, 0);
  }
  return acc;
}

// stage 32 rows x 512 bf16 from global into padded LDS rows
__device__ __forceinline__ void stage32(const unsigned short* g, char* dst, int tid){
  int b = tid & 31, seg = tid >> 5;
  const float4* s4 = (const float4*)(g + (size_t)b*512 + seg*64);
  float4* d4 = (float4*)(dst + b*ROWB + seg*128);
  #pragma unroll
  for (int i=0;i<8;i++) d4[i] = s4[i];
}

__device__ __forceinline__ float dot512(const float* __restrict__ x, const float* __restrict__ w){
  const float4* x4 = (const float4*)x;
  const float4* w4 = (const float4*)w;
  float a0=0.f,a1=0.f,a2=0.f,a3=0.f;
  #pragma unroll 8
  for (int h=0; h<128; h++){
    float4 xx = x4[h]; float4 ww = w4[h];
    a0 = fmaf(xx.x, ww.x, a0); a1 = fmaf(xx.y, ww.y, a1);
    a2 = fmaf(xx.z, ww.z, a2); a3 = fmaf(xx.w, ww.w, a3);
  }
  return (a0+a1)+(a2+a3);
}

struct ScanArgs {
  const int* inputs; const int* topics; const float* out0;
  const float* h0in; const float* c0in; const float* mask; const float* cover;
  const float* emb; const float* Uf; const float* Ua; const float* Wa;
  const float* vaw; const float* vab;
  const float* wih0; const float* whh0; const float* bih0; const float* bhh0;
  const float* wih1; const float* whh1; const float* bih1; const float* bhh1;
  char* ws; float* out;
};

// 208 wgs x 256 threads, 1 wg/CU (100KB LDS). wgs 0..79 attention, 80..207 LSTM.
__global__ __launch_bounds__(256) void scan_kernel(ScanArgs a){
  extern __shared__ char sm[];
  cg::grid_group grid = cg::this_grid();
  const int wg = blockIdx.x, tid = threadIdx.x;
  const int lane = tid & 63, wave = tid >> 6;
  const int GT = gridDim.x * blockDim.x;
  const int gt = wg*256 + tid;
  char* wsb = a.ws;
  const bool isAttn = (wg < 80);
  const int head = wg >> 4;            // attn: 0..4
  const int e0 = (wg & 15) * 32;       // attn e-slice
  const int lw = wg - 80;              // lstm index 0..127
  const int u0 = lw * 4;               // lstm u-slice

  // persistent per-thread registers
  f32x4 pkr = {0.f,0.f,0.f,0.f};
  float var[4] = {0.f,0.f,0.f,0.f};
  float b0r[4] = {0,0,0,0}, b1r[4] = {0,0,0,0};
  float c0r = 0.f, c1r = 0.f;
  float covr[NK] = {0,0,0,0,0}, phir[NK] = {1,1,1,1,1};

  // ================= P0a: inits + phi =================
  {
    unsigned short* qb  = (unsigned short*)(wsb + QB_B);
    unsigned short* h1b = (unsigned short*)(wsb + H1B_B);
    unsigned short* h0b = (unsigned short*)(wsb + H0B_B);
    for (int i = gt; i < NB*NH; i += GT){
      qb[i]  = f2b16(a.out0[i]);
      h1b[i] = f2b16(a.h0in[NB*NH + i]);
      h0b[i] = f2b16(a.h0in[i]);
    }
    for (int i = gt; i < 2*160; i += GT) ((float*)(wsb + SBUF_B))[i] = 0.f;
    if (gt < 160){
      int b = gt/NK, k = gt%NK;
      float ms = 0.f; for (int s=0;s<NS;s++) ms += a.mask[b*NS+s];
      float acc = 0.f;
      for (int kk=0; kk<NK; kk++){
        const float* te = a.emb + (size_t)a.topics[b*NK+kk]*NE;
        const float* uf = a.Uf + (size_t)k*(NK*NE) + kk*NE;
        acc += dot512(te, uf);
      }
      ((float*)(wsb + PHI_B))[gt] = ms * sigmf(acc);
    }
  }
  grid.sync();

  // ================= P1: Wa powers (fp32, into ws) =================
  for (int r=0; r<4; r++){
    const float* Asrc = (r==0) ? a.Wa : (const float*)(wsb + PWR_B) + (size_t)(r-1)*NH*NH;
    float* Mo = (float*)(wsb + PWR_B) + (size_t)r*NH*NH;
    for (int d = gt; d < NH*NH; d += GT){
      int row = d >> 9, col = d & 511;
      const float* ar = Asrc + (size_t)row*NH;
      float acc = 0.f;
      for (int k2=0;k2<NH;k2++) acc = fmaf(ar[k2], a.Wa[(size_t)k2*NH + col], acc);
      Mo[d] = acc;
    }
    grid.sync();
  }

  // ================= P2: attn pk+Mi load; lstm tp =================
  if (isAttn){
    // pk: A = Ua rows (e-slice), B = topic_e rows for this head
    for (int idx=tid; idx<32*512; idx+=256){
      int r = idx>>9, k = idx&511;
      *(unsigned short*)(sm + A_MI + r*ROWB + k*2) = f2b16(a.Ua[(size_t)(e0+r)*NE + k]);
    }
    for (int idx=tid; idx<32*512; idx+=256){
      int r = idx>>9, k = idx&511;
      int tok = a.topics[r*NK + head];
      *(unsigned short*)(sm + A_ACT + r*ROWB + k*2) = f2b16(a.emb[(size_t)tok*NE + k]);
    }
    __syncthreads();
    {
      int mt = wave&1, nt = wave>>1;
      pkr = chain16(sm + A_MI + mt*16*ROWB, sm + A_ACT + nt*16*ROWB, lane);
      int lq = lane>>4;
      #pragma unroll
      for (int r2=0;r2<4;r2++) var[r2] = a.vaw[e0 + mt*16 + lq*4 + r2];
    }
    __syncthreads();
    // Mi slice -> LDS bf16 (Mi = Wa^(head+1))
    const float* Msrc = (head==0) ? a.Wa : (const float*)(wsb + PWR_B) + (size_t)(head-1)*NH*NH;
    for (int idx=tid; idx<32*512; idx+=256){
      int r = idx>>9, k = idx&511;
      *(unsigned short*)(sm + A_MI + r*ROWB + k*2) = f2b16(Msrc[(size_t)(e0+r)*NH + k]);
    }
  } else {
    // wihm (mt-half of wih0) rows -> WI temp
    for (int idx=tid; idx<16*512; idx+=256){
      int rr = idx>>9, k = idx&511;
      int j = (rr>>2)*NH + u0 + (rr&3);
      *(unsigned short*)(sm + L_WI + rr*ROWB + k*2) = f2b16(a.wih0[(size_t)j*(2*NE) + NE + k]);
    }
    __syncthreads();
    // tp[b][k][rr] = topic_e[b,k] . wihm[rr]
    for (int rnd=0; rnd<5; rnd++){
      for (int idx=tid; idx<32*512; idx+=256){
        int r = idx>>9, k = idx&511;
        int tok = a.topics[rnd*32 + r];
        *(unsigned short*)(sm + L_ACT + r*ROWB + k*2) = f2b16(a.emb[(size_t)tok*NE + k]);
      }
      __syncthreads();
      if (wave < 2){
        f32x4 acc = chain16(sm + L_ACT + wave*16*ROWB, sm + L_WI, lane);
        int lr = lane&15, lq = lane>>4;
        #pragma unroll
        for (int r2=0;r2<4;r2++){
          int row = rnd*32 + wave*16 + lq*4 + r2;
          int bb = row/5, kk = row - bb*5;
          *(float*)(sm + L_TP + (((kk*16) + lr)*32 + bb)*4) = acc[r2];
        }
      }
      __syncthreads();
    }
  }
  grid.sync();   // P3: attn done reading powers; ghE may now overwrite

  // ================= P4: lstm ghE + weights + regs + gh0 init =================
  if (!isAttn){
    // wihE rows -> temp
    for (int idx=tid; idx<16*512; idx+=256){
      int rr = idx>>9, k = idx&511;
      int j = (rr>>2)*NH + u0 + (rr&3);
      *(unsigned short*)(sm + 66560 + rr*ROWB + k*2) = f2b16(a.wih0[(size_t)j*(2*NE) + k]);
    }
    __syncthreads();
    unsigned short* gE = (unsigned short*)(wsb + GHE_B);
    for (int it=0; it<32; it++){
      for (int idx=tid; idx<64*512; idx+=256){
        int r = idx>>9, k = idx&511;
        int grow = it*64 + r;
        int tt = grow>>5, bb = grow&31;
        int tok = a.inputs[bb*NS + tt];
        *(unsigned short*)(sm + r*ROWB + k*2) = f2b16(a.emb[(size_t)tok*NE + k]);
      }
      __syncthreads();
      {
        f32x4 acc = chain16(sm + wave*16*ROWB, sm + 66560, lane);
        int lr = lane&15, lq = lane>>4;
        #pragma unroll
        for (int r2=0;r2<4;r2++){
          int grow = it*64 + wave*16 + lq*4 + r2;
          int tt = grow>>5, bb = grow&31;
          int jg = (lr>>2)*NH + u0 + (lr&3);
          gE[((size_t)tt*2048 + jg)*32 + bb] = f2b16(acc[r2]);
        }
      }
      __syncthreads();
    }
    // persistent weights
    for (int idx=tid; idx<16*512; idx+=256){
      int rr = idx>>9, k = idx&511;
      int j = (rr>>2)*NH + u0 + (rr&3);
      *(unsigned short*)(sm + L_W1 + rr*ROWB + k*2) = f2b16(a.whh1[(size_t)j*NH + k]);
      *(unsigned short*)(sm + L_WI + rr*ROWB + k*2) = f2b16(a.wih1[(size_t)j*NH + k]);
      *(unsigned short*)(sm + L_W0 + rr*ROWB + k*2) = f2b16(a.whh0[(size_t)j*NH + k]);
    }
    if (tid < 128){
      int bb = tid&31, ur = tid>>5;
      #pragma unroll
      for (int g=0; g<4; g++){
        int j = g*NH + u0 + ur;
        b0r[g] = a.bih0[j] + a.bhh0[j];
        b1r[g] = a.bih1[j] + a.bhh1[j];
      }
      c0r = a.c0in[(size_t)bb*NH + u0 + ur];
      c1r = a.c0in[(size_t)NB*NH + bb*NH + u0 + ur];
    }
    if (tid < 32){
      const float* phiG = (const float*)(wsb + PHI_B);
      #pragma unroll
      for (int k=0;k<NK;k++){ covr[k] = a.cover[tid*NK + k]; phir[k] = phiG[tid*NK + k]; }
    }
    __syncthreads();
    // gh0 init from h0(0)
    stage32((const unsigned short*)(wsb + H0B_B), sm + L_ACT, tid);
    __syncthreads();
    if (wave & 1){
      int nt = wave>>1;
      f32x4 acc = chain16(sm + L_W0, sm + L_ACT + nt*16*ROWB, lane);
      int lr = lane&15, lq = lane>>4;
      #pragma unroll
      for (int r2=0;r2<4;r2++)
        *(float*)(sm + L_GH0 + ((lq*4+r2)*32 + nt*16 + lr)*4) = acc[r2];
    }
  }
  grid.sync();   // P5: enter scan

  // ================= scan =================
  for (int t=0; t<NS; t++){
    // ---- Phase A ----
    if (isAttn){
      stage32((const unsigned short*)(wsb + QB_B), sm + A_ACT, tid);
      __syncthreads();
      int mt = wave&1, nt = wave>>1;
      f32x4 acc = chain16(sm + A_MI + mt*16*ROWB, sm + A_ACT + nt*16*ROWB, lane);
      float v = 0.f;
      #pragma unroll
      for (int r2=0;r2<4;r2++) v += tanhf(acc[r2] + pkr[r2]) * var[r2];
      v += __shfl_xor(v, 16);
      v += __shfl_xor(v, 32);
      if ((lane>>4)==0) *(float*)(sm + A_SCR + (wave*16 + (lane&15))*4) = v;
      __syncthreads();
      if (tid < 32){
        int nt2 = tid>>4, bh = tid&15;
        float s = *(const float*)(sm + A_SCR + ((nt2*2)*16 + bh)*4)
                + *(const float*)(sm + A_SCR + ((nt2*2+1)*16 + bh)*4);
        atomicAdd((float*)(wsb + SBUF_B) + (t&1)*160 + (nt2*16+bh)*NK + head, s);
      }
    } else {
      stage32((const unsigned short*)(wsb + H1B_B), sm + L_ACT, tid);
      __syncthreads();
      if (wave < 2){
        f32x4 acc = chain16(sm + L_W1, sm + L_ACT + wave*16*ROWB, lane);
        int lr = lane&15, lq = lane>>4;
        #pragma unroll
        for (int r2=0;r2<4;r2++)
          *(float*)(sm + L_GH1 + ((lq*4+r2)*32 + wave*16 + lr)*4) = acc[r2];
      }
    }
    grid.sync();

    // ---- Phase C: softmax (replicated) + cell0 ----
    if (!isAttn){
      if (tid < 32){
        const float* sb = (const float*)(wsb + SBUF_B) + (t&1)*160 + tid*NK;
        float vb = a.vab[0];
        float sc[NK], mx = -1e30f;
        #pragma unroll
        for (int k=0;k<NK;k++){ float s = (sb[k] + vb) * covr[k]; sc[k] = s; mx = fmaxf(mx, s); }
        float sum = 0.f;
        #pragma unroll
        for (int k=0;k<NK;k++){ sc[k] = expf(sc[k]-mx); sum += sc[k]; }
        float inv = 1.0f/sum;
        #pragma unroll
        for (int k=0;k<NK;k++){
          float al = sc[k]*inv;
          *(float*)(sm + L_AL + (tid*NK+k)*4) = al;
          covr[k] = covr[k] - al/phir[k];
          if (lw == 0){
            a.out[O_ATTN + (size_t)(t*NB + tid)*NK + k] = al;
            if (t == NS-1) a.out[O_COVF + tid*NK + k] = covr[k];
          }
        }
      }
      __syncthreads();
      if (tid < 128){
        int bb = tid&31, ur = tid>>5;
        const unsigned short* gE = (const unsigned short*)(wsb + GHE_B);
        float al[NK];
        #pragma unroll
        for (int k=0;k<NK;k++) al[k] = *(const float*)(sm + L_AL + (bb*NK+k)*4);
        float g4[4];
        #pragma unroll
        for (int g=0; g<4; g++){
          int rr = g*4 + ur;
          float x = b2f16(gE[((size_t)t*2048 + g*NH + u0 + ur)*32 + bb]);
          x += *(const float*)(sm + L_GH0 + (rr*32 + bb)*4);
          x += b0r[g];
          #pragma unroll
          for (int k=0;k<NK;k++) x += al[k] * *(const float*)(sm + L_TP + ((k*16+rr)*32 + bb)*4);
          g4[g] = x;
        }
        float cn = sigmf(g4[1])*c0r + sigmf(g4[0])*tanhf(g4[2]);
        float hn = sigmf(g4[3])*tanhf(cn);
        c0r = cn;
        ((unsigned short*)(wsb + H0B_B))[(size_t)bb*NH + u0 + ur] = f2b16(hn);
        if (t == NS-1){
          a.out[O_HF + (size_t)bb*NH + u0 + ur] = hn;
          a.out[O_CF + (size_t)bb*NH + u0 + ur] = cn;
        }
      }
    }
    grid.sync();

    // ---- Phase D: cell1 + gh0 for next step ----
    if (!isAttn){
      stage32((const unsigned short*)(wsb + H0B_B), sm + L_ACT, tid);
      __syncthreads();
      {
        int mat = wave&1, nt = wave>>1;
        f32x4 acc = chain16(sm + (mat ? L_W0 : L_WI), sm + L_ACT + nt*16*ROWB, lane);
        int lr = lane&15, lq = lane>>4;
        char* dst = sm + (mat ? L_GH0 : L_GB);
        #pragma unroll
        for (int r2=0;r2<4;r2++)
          *(float*)(dst + ((lq*4+r2)*32 + nt*16 + lr)*4) = acc[r2];
      }
      __syncthreads();
      if (tid < 128){
        int bb = tid&31, ur = tid>>5;
        float g4[4];
        #pragma unroll
        for (int g=0; g<4; g++){
          int rr = g*4+ur;
          g4[g] = *(const float*)(sm + L_GB + (rr*32+bb)*4)
                + *(const float*)(sm + L_GH1 + (rr*32+bb)*4) + b1r[g];
        }
        float cn = sigmf(g4[1])*c1r + sigmf(g4[0])*tanhf(g4[2]);
        float hn = sigmf(g4[3])*tanhf(cn);
        c1r = cn;
        unsigned short hb = f2b16(hn);
        ((unsigned short*)(wsb + QB_B))[(size_t)bb*NH + u0 + ur] = hb;
        ((unsigned short*)(wsb + H1B_B))[(size_t)bb*NH + u0 + ur] = hb;
        a.out[O_OUTS + (size_t)(t*NB + bb)*NH + u0 + ur] = hn;
        if (t == NS-1){
          a.out[O_HF + (size_t)(NB + bb)*NH + u0 + ur] = hn;
          a.out[O_CF + (size_t)(NB + bb)*NH + u0 + ur] = cn;
        }
      }
    } else if (wg == 0 && tid < 160){
      ((float*)(wsb + SBUF_B))[(t&1)*160 + tid] = 0.f;   // re-zero for step t+2
    }
    grid.sync();
  }
}

// ================= adaptive log-softmax (round-0, proven) =================

__global__ __launch_bounds__(256) void kproj(const float* __restrict__ X,
                                             const float* __restrict__ t1w1,
                                             const float* __restrict__ t2w1,
                                             float* __restrict__ P1, float* __restrict__ P2){
  __shared__ float xs[16*516];
  int r0 = blockIdx.x*16, tid = threadIdx.x;
  for (int idx=tid; idx<16*512; idx+=256){ int rl=idx>>9, h=idx&511; xs[rl*516+h] = X[(size_t)(r0+rl)*NH + h]; }
  __syncthreads();
  for (int k=0;k<8;k++){
    int d = tid + 256*k; int rl = d & 15, c = d >> 4;
    P1[(size_t)(r0+rl)*128 + c] = dot512(xs + rl*516, t1w1 + (size_t)c*NH);
  }
  for (int k=0;k<2;k++){
    int d = tid + 256*k; int rl = d & 15, c = d >> 4;
    P2[(size_t)(r0+rl)*32 + c] = dot512(xs + rl*516, t2w1 + (size_t)c*NH);
  }
}

__global__ __launch_bounds__(256) void khead(const float* __restrict__ X,
                                             const float* __restrict__ hw,
                                             const int* __restrict__ tgt,
                                             float* __restrict__ sums,
                                             float* __restrict__ hlt, float* __restrict__ hc1, float* __restrict__ hc2){
  __shared__ float xs[16*516];
  __shared__ float red[256];
  int r0 = blockIdx.x*16, tid = threadIdx.x;
  int c0 = blockIdx.y*251;
  int cend = min(2502, c0+251);
  for (int idx=tid; idx<16*512; idx+=256){ int rl=idx>>9, h=idx&511; xs[rl*516+h] = X[(size_t)(r0+rl)*NH + h]; }
  __syncthreads();
  int b16 = tid & 15, cg = tid >> 4;
  int row = r0 + b16;
  int srow = row >> 5, brow = row & 31;
  int tg = tgt[brow*NS + srow];
  int cap = tg < C1V ? tg : (C1V-1);
  float lsum = 0.f;
  const float4* x4 = (const float4*)(xs + b16*516);
  for (int kk0 = 0; kk0 < 16; kk0 += 8){
    float acc[8];
    const float4* wp[8];
    #pragma unroll
    for (int j=0;j<8;j++){
      acc[j] = 0.f;
      int c = c0 + cg + (kk0+j)*16;
      wp[j] = (const float4*)(hw + (size_t)(c < cend ? c : c0)*NH);
    }
    #pragma unroll 2
    for (int h=0; h<128; h++){
      float4 xx = x4[h];
      #pragma unroll
      for (int j=0;j<8;j++){
        float4 ww = wp[j][h];
        acc[j] = fmaf(xx.x, ww.x, acc[j]); acc[j] = fmaf(xx.y, ww.y, acc[j]);
        acc[j] = fmaf(xx.z, ww.z, acc[j]); acc[j] = fmaf(xx.w, ww.w, acc[j]);
      }
    }
    #pragma unroll
    for (int j=0;j<8;j++){
      int c = c0 + cg + (kk0+j)*16;
      if (c < cend){
        float v = acc[j];
        lsum += __expf(v);
        if (c == cap) hlt[row] = v;
        else if (c == C1V) hc1[row] = v;
        else if (c == C1V+1) hc2[row] = v;
      }
    }
  }
  red[tid] = lsum;
  __syncthreads();
  if (tid < 16){
    float s2 = 0.f;
    for (int g=0; g<16; g++) s2 += red[g*16 + tid];
    atomicAdd(&sums[r0 + tid], s2);
  }
}

__global__ __launch_bounds__(256) void ktail1(const float* __restrict__ P1,
                                              const float* __restrict__ w2t,
                                              const int* __restrict__ tgt,
                                              float* __restrict__ sums, float* __restrict__ l1p){
  __shared__ int rlist[16];
  __shared__ float rsum[16];
  __shared__ int rcnt;
  int r0 = blockIdx.x*16, tid = threadIdx.x;
  if (tid == 0) rcnt = 0;
  __syncthreads();
  if (tid < 16){
    rsum[tid] = 0.f;
    int row = r0 + tid;
    int tg = tgt[(row&31)*NS + (row>>5)];
    if (tg >= C1V && tg < C2V){
      int i = atomicAdd(&rcnt, 1);
      rlist[i] = (tid << 16) | (tg - C1V);
    }
  }
  __syncthreads();
  int m = rcnt;
  if (m == 0) return;
  int rl = tid & 15, cg = tid >> 4;
  if (rl < m){
    int pkd = rlist[rl];
    int lrow = pkd >> 16, tl = pkd & 0xffff;
    int orow = r0 + lrow;
    float4 pr[32];
    const float4* p4 = (const float4*)(P1 + (size_t)orow*128);
    #pragma unroll
    for (int h=0;h<32;h++) pr[h] = p4[h];
    int c0 = blockIdx.y*750, cend = min(CSZ1V, c0+750);
    float lsum = 0.f;
    for (int c = c0 + cg; c < cend; c += 16){
      const float4* w4 = (const float4*)(w2t + (size_t)c*128);
      float a0=0.f,a1=0.f,a2=0.f,a3=0.f;
      #pragma unroll
      for (int h=0;h<32;h++){
        float4 ww = w4[h];
        a0=fmaf(pr[h].x,ww.x,a0); a1=fmaf(pr[h].y,ww.y,a1);
        a2=fmaf(pr[h].z,ww.z,a2); a3=fmaf(pr[h].w,ww.w,a3);
      }
      float v = (a0+a1)+(a2+a3);
      lsum += __expf(v);
      if (c == tl) l1p[orow] = v;
    }
    atomicAdd(&rsum[lrow], lsum);
  }
  __syncthreads();
  if (tid < 16 && rsum[tid] != 0.f) atomicAdd(&sums[2048 + r0 + tid], rsum[tid]);
}

__global__ __launch_bounds__(256) void ktail2(const float* __restrict__ P2,
                                              const float* __restrict__ w2t,
                                              const int* __restrict__ tgt,
                                              float* __restrict__ sums, float* __restrict__ l2p){
  __shared__ int rlist[16];
  __shared__ float rsum[16];
  __shared__ int rcnt;
  int r0 = blockIdx.x*16, tid = threadIdx.x;
  if (tid == 0) rcnt = 0;
  __syncthreads();
  if (tid < 16){
    rsum[tid] = 0.f;
    int row = r0 + tid;
    int tg = tgt[(row&31)*NS + (row>>5)];
    if (tg >= C2V){
      int i = atomicAdd(&rcnt, 1);
      rlist[i] = (tid << 16) | (tg - C2V);
    }
  }
  __syncthreads();
  int m = rcnt;
  if (m == 0) return;
  int rl = tid & 15, cg = tid >> 4;
  if (rl < m){
    int pkd = rlist[rl];
    int lrow = pkd >> 16, tl = pkd & 0xffff;
    int orow = r0 + lrow;
    float4 pr[8];
    const float4* p4 = (const float4*)(P2 + (size_t)orow*32);
    #pragma unroll
    for (int h=0;h<8;h++) pr[h] = p4[h];
    int c0 = blockIdx.y*2500, cend = min(CSZ2V, c0+2500);
    float lsum = 0.f;
    for (int c = c0 + cg; c < cend; c += 16){
      const float4* w4 = (const float4*)(w2t + (size_t)c*32);
      float a0=0.f,a1=0.f,a2=0.f,a3=0.f;
      #pragma unroll
      for (int h=0;h<8;h++){
        float4 ww = w4[h];
        a0=fmaf(pr[h].x,ww.x,a0); a1=fmaf(pr[h].y,ww.y,a1);
        a2=fmaf(pr[h].z,ww.z,a2); a3=fmaf(pr[h].w,ww.w,a3);
      }
      float v = (a0+a1)+(a2+a3);
      lsum += __expf(v);
      if (c == tl) l2p[orow] = v;
    }
    atomicAdd(&rsum[lrow], lsum);
  }
  __syncthreads();
  if (tid < 16 && rsum[tid] != 0.f) atomicAdd(&sums[4096 + r0 + tid], rsum[tid]);
}

__global__ __launch_bounds__(256) void kfinal(const float* __restrict__ sums,
                                              const float* __restrict__ hlt, const float* __restrict__ hc1,
                                              const float* __restrict__ hc2, const float* __restrict__ l1p,
                                              const float* __restrict__ l2p, const int* __restrict__ tgt,
                                              float* __restrict__ out){
  __shared__ float red[256];
  int tid = threadIdx.x;
  float acc = 0.f;
  for (int n = tid; n < 2048; n += 256){
    int s = n >> 5, b = n & 31;
    int tg = tgt[b*NS + s];
    float lsh = logf(sums[n]);
    float v;
    if (tg < C1V) v = hlt[n] - lsh;
    else if (tg < C2V) v = (hc1[n] - lsh) + (l1p[n] - logf(sums[2048+n]));
    else v = (hc2[n] - lsh) + (l2p[n] - logf(sums[4096+n]));
    out[O_LP + n] = v;
    acc += v;
  }
  red[tid] = acc;
  __syncthreads();
  for (int off=128; off>0; off>>=1){ if (tid<off) red[tid] += red[tid+off]; __syncthreads(); }
  if (tid==0) out[O_LOSS] = -red[0] / 2048.0f;
}

extern "C" void kernel_launch(void* const* d_in, const int* in_sizes, int n_in,
                              void* d_out, int out_size, void* d_ws, size_t ws_size,
                              hipStream_t stream){
  (void)in_sizes; (void)n_in; (void)out_size; (void)ws_size;
  ScanArgs sa;
  sa.inputs = (const int*)d_in[0];
  sa.topics = (const int*)d_in[1];
  sa.out0   = (const float*)d_in[2];
  sa.h0in   = (const float*)d_in[3];
  sa.c0in   = (const float*)d_in[4];
  sa.mask   = (const float*)d_in[5];
  sa.cover  = (const float*)d_in[7];
  sa.emb    = (const float*)d_in[8];
  sa.Uf     = (const float*)d_in[9];
  sa.Ua     = (const float*)d_in[10];
  sa.Wa     = (const float*)d_in[11];
  sa.vaw    = (const float*)d_in[12];
  sa.vab    = (const float*)d_in[13];
  sa.wih0   = (const float*)d_in[14];
  sa.whh0   = (const float*)d_in[15];
  sa.bih0   = (const float*)d_in[16];
  sa.bhh0   = (const float*)d_in[17];
  sa.wih1   = (const float*)d_in[18];
  sa.whh1   = (const float*)d_in[19];
  sa.bih1   = (const float*)d_in[20];
  sa.bhh1   = (const float*)d_in[21];
  sa.ws  = (char*)d_ws;
  sa.out = (float*)d_out;

  char* wsb = (char*)d_ws;
  const int* target = (const int*)d_in[6];
  float* outf = (float*)d_out;

  hipMemsetAsync(wsb + SUMS_B, 0, 6144*sizeof(float), stream);

  static int lds_set = 0;
  if (!lds_set){   // host-side attribute set; idempotent, not a stream op
    hipFuncSetAttribute((const void*)scan_kernel,
                        hipFuncAttributeMaxDynamicSharedMemorySize, LDS_BYTES);
    lds_set = 1;
  }

  void* args[] = { (void*)&sa };
  hipLaunchCooperativeKernel((void*)scan_kernel, dim3(208), dim3(256), args, LDS_BYTES, stream);

  const float* X = outf + O_OUTS;   // outs is exactly [2048][512] row-major
  kproj<<<dim3(128),dim3(256),0,stream>>>(X, (const float*)d_in[23], (const float*)d_in[25],
                                          (float*)(wsb+P1_B), (float*)(wsb+P2_B));
  khead<<<dim3(128,10),dim3(256),0,stream>>>(X, (const float*)d_in[22], target,
           (float*)(wsb+SUMS_B), (float*)(wsb+HLT_B), (float*)(wsb+HC1_B), (float*)(wsb+HC2_B));
  ktail1<<<dim3(128,10),dim3(256),0,stream>>>((const float*)(wsb+P1_B), (const float*)d_in[24], target,
           (float*)(wsb+SUMS_B), (float*)(wsb+L1P_B));
  ktail2<<<dim3(128,16),dim3(256),0,stream>>>((const float*)(wsb+P2_B), (const float*)d_in[26], target,
           (float*)(wsb+SUMS_B), (float*)(wsb+L2P_B));
  kfinal<<<dim3(1),dim3(256),0,stream>>>((const float*)(wsb+SUMS_B),
           (const float*)(wsb+HLT_B), (const float*)(wsb+HC1_B), (const float*)(wsb+HC2_B),
           (const float*)(wsb+L1P_B), (const float*)(wsb+L2P_B), target, outf);
}

// Round 3
// 4074.936 us; speedup vs baseline: 2.8388x; 1.7426x over previous
//
#include <hip/hip_runtime.h>
#include <cmath>

typedef __attribute__((ext_vector_type(8))) short short8;
typedef __attribute__((ext_vector_type(4))) float f32x4;

#define NB 32
#define NS 64
#define NK 5
#define NE 512
#define NH 512
#define C1V 2500
#define C2V 10000
#define CSZ1V 7500
#define CSZ2V 40000

// ---- workspace BYTE offsets ----
#define PWR_B   0u          // 4*512*512 f32 = 4MB (preamble only; aliased by ghE)
#define GHE_B   0u          // 64*2048*32 bf16 = 8MB
#define QB_B    8388608u    // 32*512 bf16
#define H1B_B   8421376u
#define H0B_B   8454144u
#define PHI_B   8488192u    // 160 f32
#define P1_B    8488832u    // 2048*128 f32
#define P2_B    9537408u    // 2048*32 f32
#define SUMS_B  9799552u    // 3*2048 f32
#define HLT_B   9824128u
#define HC1_B   9832320u
#define HC2_B   9840512u
#define L1P_B   9848704u
#define L2P_B   9856896u
#define BAR_B   9865216u    // flags 208*64B = 13312, go at +13312; memset 16384
#define SB2_B   9881600u    // 80*32 f32 score partials; end 9,891,840 (< 10.9MB proven)

// ---- d_out float offsets (verified) ----
#define O_LP   0
#define O_LOSS 2048
#define O_OUTS 2049
#define O_HF   1050625
#define O_CF   1083393
#define O_ATTN 1116161
#define O_COVF 1126401

// ---- LDS byte offsets ----
#define ROWB 1040           // 520 bf16 per padded row
#define L_W1  0
#define L_WI  16640
#define L_W0  33280
#define L_ACT 49920
#define L_TP  83200
#define L_GH1 93440
#define L_GH0 95488
#define L_GB  97536
#define L_AL  99584
#define LDS_BYTES 100352
#define A_MI  0
#define A_ACT 33280
#define A_SCR 66560

__device__ __forceinline__ float sigmf(float x){ return 1.0f/(1.0f + expf(-x)); }

__device__ __forceinline__ unsigned short f2b16(float f){
  unsigned u = __float_as_uint(f);
  return (unsigned short)((u + 0x7fffu + ((u>>16)&1u)) >> 16);
}
__device__ __forceinline__ float b2f16(unsigned short s){ return __uint_as_float(((unsigned)s)<<16); }

// ---- flag barrier (no contended RMW; collector = wg0) ----
__device__ __forceinline__ unsigned ldf(unsigned* p){
  return __hip_atomic_load(p, __ATOMIC_RELAXED, __HIP_MEMORY_SCOPE_AGENT);
}
__device__ __forceinline__ void stf(unsigned* p, unsigned v){
  __hip_atomic_store(p, v, __ATOMIC_RELAXED, __HIP_MEMORY_SCOPE_AGENT);
}
__device__ __forceinline__ void bar_arrive(unsigned* flags, int wg, unsigned gen, int tid){
  __syncthreads();
  if (tid == 0){
    __threadfence();                 // release: drain + wb L2 -> coherence point
    stf(flags + wg*16, gen);
  }
}
__device__ __forceinline__ void bar_collect(unsigned* flags, unsigned* go, unsigned gen,
                                            int first, int cnt, int tid){
  for (int i = tid; i < cnt; i += 256){
    unsigned* f = flags + (first + i)*16;
    while (ldf(f) < gen) __builtin_amdgcn_s_sleep(1);
  }
  __syncthreads();
  if (tid == 0) stf(go, gen);
}
__device__ __forceinline__ void bar_wait(unsigned* go, unsigned gen, int tid){
  if (tid == 0){
    while (ldf(go) < gen) __builtin_amdgcn_s_sleep(1);
    __threadfence();                 // acquire: inv L1/L2 -> fresh reads
  }
  __syncthreads();
}

// D[m][n] += A[m][k]*B[n][k] over K=512, one 16x16 tile, rows padded ROWB.
__device__ __forceinline__ f32x4 chain16(const char* Abase, const char* Bbase, int lane){
  f32x4 acc = {0.f,0.f,0.f,0.f};
  int lr = lane & 15, lq = lane >> 4;
  const char* ap = Abase + lr*ROWB + lq*16;
  const char* bp = Bbase + lr*ROWB + lq*16;
  #pragma unroll
  for (int ks=0; ks<16; ks++){
    short8 af = *(const short8*)(ap + ks*64);
    short8 bf = *(const short8*)(bp + ks*64);
    acc = __builtin_amdgcn_mfma_f32_16x16x32_bf16(af, bf, acc, 0, 0, 0);
  }
  return acc;
}

__device__ __forceinline__ void stage32(const unsigned short* g, char* dst, int tid){
  int b = tid & 31, seg = tid >> 5;
  const float4* s4 = (const float4*)(g + (size_t)b*512 + seg*64);
  float4* d4 = (float4*)(dst + b*ROWB + seg*128);
  #pragma unroll
  for (int i=0;i<8;i++) d4[i] = s4[i];
}

__device__ __forceinline__ float dot512(const float* __restrict__ x, const float* __restrict__ w){
  const float4* x4 = (const float4*)x;
  const float4* w4 = (const float4*)w;
  float a0=0.f,a1=0.f,a2=0.f,a3=0.f;
  #pragma unroll 8
  for (int h=0; h<128; h++){
    float4 xx = x4[h]; float4 ww = w4[h];
    a0 = fmaf(xx.x, ww.x, a0); a1 = fmaf(xx.y, ww.y, a1);
    a2 = fmaf(xx.z, ww.z, a2); a3 = fmaf(xx.w, ww.w, a3);
  }
  return (a0+a1)+(a2+a3);
}

struct ScanArgs {
  const int* inputs; const int* topics; const float* out0;
  const float* h0in; const float* c0in; const float* mask; const float* cover;
  const float* emb; const float* Uf; const float* Ua; const float* Wa;
  const float* vaw; const float* vab;
  const float* wih0; const float* whh0; const float* bih0; const float* bhh0;
  const float* wih1; const float* whh1; const float* bih1; const float* bhh1;
  char* ws; float* out;
};

// 208 wgs x 256 threads. wgs 0..79 attention (wg0 = barrier collector), 80..207 LSTM.
__global__ __launch_bounds__(256) void scan_kernel(ScanArgs a){
  extern __shared__ char sm[];
  const int wg = blockIdx.x, tid = threadIdx.x;
  const int lane = tid & 63, wave = tid >> 6;
  const int GT = gridDim.x * blockDim.x;
  const int gt = wg*256 + tid;
  char* wsb = a.ws;
  unsigned* bflags = (unsigned*)(wsb + BAR_B);
  unsigned* bgo    = (unsigned*)(wsb + BAR_B + 13312);
  const bool isAttn = (wg < 80);
  const int head = wg >> 4;
  const int e0 = (wg & 15) * 32;
  const int lw = wg - 80;
  const int u0 = lw * 4;

  f32x4 pkr = {0.f,0.f,0.f,0.f};
  float var[4] = {0.f,0.f,0.f,0.f};
  float b0r[4] = {0,0,0,0}, b1r[4] = {0,0,0,0};
  float c0r = 0.f, c1r = 0.f;
  float covr[NK] = {0,0,0,0,0}, phir[NK] = {1,1,1,1,1};

  // ================= P0a: inits + phi =================
  {
    unsigned short* qb  = (unsigned short*)(wsb + QB_B);
    unsigned short* h1b = (unsigned short*)(wsb + H1B_B);
    unsigned short* h0b = (unsigned short*)(wsb + H0B_B);
    for (int i = gt; i < NB*NH; i += GT){
      qb[i]  = f2b16(a.out0[i]);
      h1b[i] = f2b16(a.h0in[NB*NH + i]);
      h0b[i] = f2b16(a.h0in[i]);
    }
    if (gt < 160){
      int b = gt/NK, k = gt%NK;
      float ms = 0.f; for (int s=0;s<NS;s++) ms += a.mask[b*NS+s];
      float acc = 0.f;
      for (int kk=0; kk<NK; kk++){
        const float* te = a.emb + (size_t)a.topics[b*NK+kk]*NE;
        const float* uf = a.Uf + (size_t)k*(NK*NE) + kk*NE;
        acc += dot512(te, uf);
      }
      ((float*)(wsb + PHI_B))[gt] = ms * sigmf(acc);
    }
  }
  bar_arrive(bflags, wg, 1, tid);
  if (wg==0) bar_collect(bflags, bgo, 1, 0, 208, tid);
  bar_wait(bgo, 1, tid);

  // ================= P1: Wa powers (fp32) =================
  for (int r=0; r<4; r++){
    const float* Asrc = (r==0) ? a.Wa : (const float*)(wsb + PWR_B) + (size_t)(r-1)*NH*NH;
    float* Mo = (float*)(wsb + PWR_B) + (size_t)r*NH*NH;
    for (int d = gt; d < NH*NH; d += GT){
      int row = d >> 9, col = d & 511;
      const float* ar = Asrc + (size_t)row*NH;
      float acc = 0.f;
      for (int k2=0;k2<NH;k2++) acc = fmaf(ar[k2], a.Wa[(size_t)k2*NH + col], acc);
      Mo[d] = acc;
    }
    unsigned g = 2 + r;
    bar_arrive(bflags, wg, g, tid);
    if (wg==0) bar_collect(bflags, bgo, g, 0, 208, tid);
    bar_wait(bgo, g, tid);
  }

  // ================= P2: attn pk+Mi; lstm tp =================
  if (isAttn){
    for (int idx=tid; idx<32*512; idx+=256){
      int r = idx>>9, k = idx&511;
      *(unsigned short*)(sm + A_MI + r*ROWB + k*2) = f2b16(a.Ua[(size_t)(e0+r)*NE + k]);
    }
    for (int idx=tid; idx<32*512; idx+=256){
      int r = idx>>9, k = idx&511;
      int tok = a.topics[r*NK + head];
      *(unsigned short*)(sm + A_ACT + r*ROWB + k*2) = f2b16(a.emb[(size_t)tok*NE + k]);
    }
    __syncthreads();
    {
      int mt = wave&1, nt = wave>>1;
      pkr = chain16(sm + A_MI + mt*16*ROWB, sm + A_ACT + nt*16*ROWB, lane);
      int lq = lane>>4;
      #pragma unroll
      for (int r2=0;r2<4;r2++) var[r2] = a.vaw[e0 + mt*16 + lq*4 + r2];
    }
    __syncthreads();
    const float* Msrc = (head==0) ? a.Wa : (const float*)(wsb + PWR_B) + (size_t)(head-1)*NH*NH;
    for (int idx=tid; idx<32*512; idx+=256){
      int r = idx>>9, k = idx&511;
      *(unsigned short*)(sm + A_MI + r*ROWB + k*2) = f2b16(Msrc[(size_t)(e0+r)*NH + k]);
    }
  } else {
    for (int idx=tid; idx<16*512; idx+=256){
      int rr = idx>>9, k = idx&511;
      int j = (rr>>2)*NH + u0 + (rr&3);
      *(unsigned short*)(sm + L_WI + rr*ROWB + k*2) = f2b16(a.wih0[(size_t)j*(2*NE) + NE + k]);
    }
    __syncthreads();
    for (int rnd=0; rnd<5; rnd++){
      for (int idx=tid; idx<32*512; idx+=256){
        int r = idx>>9, k = idx&511;
        int tok = a.topics[rnd*32 + r];
        *(unsigned short*)(sm + L_ACT + r*ROWB + k*2) = f2b16(a.emb[(size_t)tok*NE + k]);
      }
      __syncthreads();
      if (wave < 2){
        f32x4 acc = chain16(sm + L_ACT + wave*16*ROWB, sm + L_WI, lane);
        int lr = lane&15, lq = lane>>4;
        #pragma unroll
        for (int r2=0;r2<4;r2++){
          int row = rnd*32 + wave*16 + lq*4 + r2;
          int bb = row/5, kk = row - bb*5;
          *(float*)(sm + L_TP + (((kk*16) + lr)*32 + bb)*4) = acc[r2];
        }
      }
      __syncthreads();
    }
  }
  // g6: attn done reading powers -> lstm may overwrite with ghE
  bar_arrive(bflags, wg, 6, tid);
  if (wg==0) bar_collect(bflags, bgo, 6, 0, 208, tid);
  if (!isAttn) bar_wait(bgo, 6, tid);

  // ================= P4 (lstm only): ghE + weights + regs + gh0 init =================
  if (!isAttn){
    for (int idx=tid; idx<16*512; idx+=256){
      int rr = idx>>9, k = idx&511;
      int j = (rr>>2)*NH + u0 + (rr&3);
      *(unsigned short*)(sm + 66560 + rr*ROWB + k*2) = f2b16(a.wih0[(size_t)j*(2*NE) + k]);
    }
    __syncthreads();
    unsigned short* gE = (unsigned short*)(wsb + GHE_B);
    for (int it=0; it<32; it++){
      for (int idx=tid; idx<64*512; idx+=256){
        int r = idx>>9, k = idx&511;
        int grow = it*64 + r;
        int tt = grow>>5, bb = grow&31;
        int tok = a.inputs[bb*NS + tt];
        *(unsigned short*)(sm + r*ROWB + k*2) = f2b16(a.emb[(size_t)tok*NE + k]);
      }
      __syncthreads();
      {
        f32x4 acc = chain16(sm + wave*16*ROWB, sm + 66560, lane);
        int lr = lane&15, lq = lane>>4;
        #pragma unroll
        for (int r2=0;r2<4;r2++){
          int grow = it*64 + wave*16 + lq*4 + r2;
          int tt = grow>>5, bb = grow&31;
          int jg = (lr>>2)*NH + u0 + (lr&3);
          gE[((size_t)tt*2048 + jg)*32 + bb] = f2b16(acc[r2]);
        }
      }
      __syncthreads();
    }
    for (int idx=tid; idx<16*512; idx+=256){
      int rr = idx>>9, k = idx&511;
      int j = (rr>>2)*NH + u0 + (rr&3);
      *(unsigned short*)(sm + L_W1 + rr*ROWB + k*2) = f2b16(a.whh1[(size_t)j*NH + k]);
      *(unsigned short*)(sm + L_WI + rr*ROWB + k*2) = f2b16(a.wih1[(size_t)j*NH + k]);
      *(unsigned short*)(sm + L_W0 + rr*ROWB + k*2) = f2b16(a.whh0[(size_t)j*NH + k]);
    }
    if (tid < 128){
      int bb = tid&31, ur = tid>>5;
      #pragma unroll
      for (int g=0; g<4; g++){
        int j = g*NH + u0 + ur;
        b0r[g] = a.bih0[j] + a.bhh0[j];
        b1r[g] = a.bih1[j] + a.bhh1[j];
      }
      c0r = a.c0in[(size_t)bb*NH + u0 + ur];
      c1r = a.c0in[(size_t)NB*NH + bb*NH + u0 + ur];
    }
    if (tid < 32){
      const float* phiG = (const float*)(wsb + PHI_B);
      #pragma unroll
      for (int k=0;k<NK;k++){ covr[k] = a.cover[tid*NK + k]; phir[k] = phiG[tid*NK + k]; }
    }
    __syncthreads();
    stage32((const unsigned short*)(wsb + H0B_B), sm + L_ACT, tid);
    __syncthreads();
    if (wave & 1){
      int nt = wave>>1;
      f32x4 acc = chain16(sm + L_W0, sm + L_ACT + nt*16*ROWB, lane);
      int lr = lane&15, lq = lane>>4;
      #pragma unroll
      for (int r2=0;r2<4;r2++)
        *(float*)(sm + L_GH0 + ((lq*4+r2)*32 + nt*16 + lr)*4) = acc[r2];
    }
    __syncthreads();
  }

  // ================= scan: gens A=7+3t, C=8+3t, D=9+3t =================
  for (int t=0; t<NS; t++){
    unsigned genA = 7 + 3*t, genC = 8 + 3*t, genD = 9 + 3*t;
    if (isAttn){
      stage32((const unsigned short*)(wsb + QB_B), sm + A_ACT, tid);
      __syncthreads();
      int mt = wave&1, nt = wave>>1;
      f32x4 acc = chain16(sm + A_MI + mt*16*ROWB, sm + A_ACT + nt*16*ROWB, lane);
      float v = 0.f;
      #pragma unroll
      for (int r2=0;r2<4;r2++) v += tanhf(acc[r2] + pkr[r2]) * var[r2];
      v += __shfl_xor(v, 16);
      v += __shfl_xor(v, 32);
      if ((lane>>4)==0) *(float*)(sm + A_SCR + (wave*16 + (lane&15))*4) = v;
      __syncthreads();
      if (tid < 32){
        int nt2 = tid>>4, bh = tid&15;
        float s = *(const float*)(sm + A_SCR + ((nt2*2)*16 + bh)*4)
                + *(const float*)(sm + A_SCR + ((nt2*2+1)*16 + bh)*4);
        ((float*)(wsb + SB2_B))[wg*32 + tid] = s;
      }
      bar_arrive(bflags, wg, genA, tid);
      if (wg == 0){
        bar_collect(bflags, bgo, genA, 0, 80, tid);
        bar_collect(bflags, bgo, genC, 80, 128, tid);
        bar_collect(bflags, bgo, genD, 80, 128, tid);
      }
      bar_wait(bgo, genD, tid);
    } else {
      // A-parallel: gh1 = whh1 . h1  (overlaps attention phase)
      stage32((const unsigned short*)(wsb + H1B_B), sm + L_ACT, tid);
      __syncthreads();
      if (wave < 2){
        f32x4 acc = chain16(sm + L_W1, sm + L_ACT + wave*16*ROWB, lane);
        int lr = lane&15, lq = lane>>4;
        #pragma unroll
        for (int r2=0;r2<4;r2++)
          *(float*)(sm + L_GH1 + ((lq*4+r2)*32 + wave*16 + lr)*4) = acc[r2];
      }
      bar_wait(bgo, genA, tid);

      // ---- Phase C ----
      if (tid < 160){
        int k = tid>>5, b = tid&31;
        const float* sb2 = (const float*)(wsb + SB2_B);
        float s = 0.f;
        #pragma unroll
        for (int es=0; es<16; es++) s += sb2[(k*16+es)*32 + b];
        *(float*)(sm + L_GB + tid*4) = s;
      }
      __syncthreads();
      if (tid < 32){
        float vb = a.vab[0];
        float sc[NK], mx = -1e30f;
        #pragma unroll
        for (int k=0;k<NK;k++){
          float s = (*(const float*)(sm + L_GB + (k*32+tid)*4) + vb) * covr[k];
          sc[k] = s; mx = fmaxf(mx, s);
        }
        float sum = 0.f;
        #pragma unroll
        for (int k=0;k<NK;k++){ sc[k] = expf(sc[k]-mx); sum += sc[k]; }
        float inv = 1.0f/sum;
        #pragma unroll
        for (int k=0;k<NK;k++){
          float al = sc[k]*inv;
          *(float*)(sm + L_AL + (tid*NK+k)*4) = al;
          covr[k] = covr[k] - al/phir[k];
          if (lw == 0){
            a.out[O_ATTN + (size_t)(t*NB + tid)*NK + k] = al;
            if (t == NS-1) a.out[O_COVF + tid*NK + k] = covr[k];
          }
        }
      }
      __syncthreads();
      if (tid < 128){
        int bb = tid&31, ur = tid>>5;
        const unsigned short* gE = (const unsigned short*)(wsb + GHE_B);
        float al[NK];
        #pragma unroll
        for (int k=0;k<NK;k++) al[k] = *(const float*)(sm + L_AL + (bb*NK+k)*4);
        float g4[4];
        #pragma unroll
        for (int g=0; g<4; g++){
          int rr = g*4 + ur;
          float x = b2f16(gE[((size_t)t*2048 + g*NH + u0 + ur)*32 + bb]);
          x += *(const float*)(sm + L_GH0 + (rr*32 + bb)*4);
          x += b0r[g];
          #pragma unroll
          for (int k=0;k<NK;k++) x += al[k] * *(const float*)(sm + L_TP + ((k*16+rr)*32 + bb)*4);
          g4[g] = x;
        }
        float cn = sigmf(g4[1])*c0r + sigmf(g4[0])*tanhf(g4[2]);
        float hn = sigmf(g4[3])*tanhf(cn);
        c0r = cn;
        ((unsigned short*)(wsb + H0B_B))[(size_t)bb*NH + u0 + ur] = f2b16(hn);
        if (t == NS-1){
          a.out[O_HF + (size_t)bb*NH + u0 + ur] = hn;
          a.out[O_CF + (size_t)bb*NH + u0 + ur] = cn;
        }
      }
      bar_arrive(bflags, wg, genC, tid);
      bar_wait(bgo, genC, tid);

      // ---- Phase D ----
      stage32((const unsigned short*)(wsb + H0B_B), sm + L_ACT, tid);
      __syncthreads();
      {
        int mat = wave&1, nt = wave>>1;
        f32x4 acc = chain16(sm + (mat ? L_W0 : L_WI), sm + L_ACT + nt*16*ROWB, lane);
        int lr = lane&15, lq = lane>>4;
        char* dst = sm + (mat ? L_GH0 : L_GB);
        #pragma unroll
        for (int r2=0;r2<4;r2++)
          *(float*)(dst + ((lq*4+r2)*32 + nt*16 + lr)*4) = acc[r2];
      }
      __syncthreads();
      if (tid < 128){
        int bb = tid&31, ur = tid>>5;
        float g4[4];
        #pragma unroll
        for (int g=0; g<4; g++){
          int rr = g*4+ur;
          g4[g] = *(const float*)(sm + L_GB + (rr*32+bb)*4)
                + *(const float*)(sm + L_GH1 + (rr*32+bb)*4) + b1r[g];
        }
        float cn = sigmf(g4[1])*c1r + sigmf(g4[0])*tanhf(g4[2]);
        float hn = sigmf(g4[3])*tanhf(cn);
        c1r = cn;
        unsigned short hb = f2b16(hn);
        ((unsigned short*)(wsb + QB_B))[(size_t)bb*NH + u0 + ur] = hb;
        ((unsigned short*)(wsb + H1B_B))[(size_t)bb*NH + u0 + ur] = hb;
        a.out[O_OUTS + (size_t)(t*NB + bb)*NH + u0 + ur] = hn;
        if (t == NS-1){
          a.out[O_HF + (size_t)(NB + bb)*NH + u0 + ur] = hn;
          a.out[O_CF + (size_t)(NB + bb)*NH + u0 + ur] = cn;
        }
      }
      bar_arrive(bflags, wg, genD, tid);
      bar_wait(bgo, genD, tid);
    }
  }
}

// ================= adaptive log-softmax (proven) =================

__global__ __launch_bounds__(256) void kproj(const float* __restrict__ X,
                                             const float* __restrict__ t1w1,
                                             const float* __restrict__ t2w1,
                                             float* __restrict__ P1, float* __restrict__ P2){
  __shared__ float xs[16*516];
  int r0 = blockIdx.x*16, tid = threadIdx.x;
  for (int idx=tid; idx<16*512; idx+=256){ int rl=idx>>9, h=idx&511; xs[rl*516+h] = X[(size_t)(r0+rl)*NH + h]; }
  __syncthreads();
  for (int k=0;k<8;k++){
    int d = tid + 256*k; int rl = d & 15, c = d >> 4;
    P1[(size_t)(r0+rl)*128 + c] = dot512(xs + rl*516, t1w1 + (size_t)c*NH);
  }
  for (int k=0;k<2;k++){
    int d = tid + 256*k; int rl = d & 15, c = d >> 4;
    P2[(size_t)(r0+rl)*32 + c] = dot512(xs + rl*516, t2w1 + (size_t)c*NH);
  }
}

__global__ __launch_bounds__(256) void khead(const float* __restrict__ X,
                                             const float* __restrict__ hw,
                                             const int* __restrict__ tgt,
                                             float* __restrict__ sums,
                                             float* __restrict__ hlt, float* __restrict__ hc1, float* __restrict__ hc2){
  __shared__ float xs[16*516];
  __shared__ float red[256];
  int r0 = blockIdx.x*16, tid = threadIdx.x;
  int c0 = blockIdx.y*251;
  int cend = min(2502, c0+251);
  for (int idx=tid; idx<16*512; idx+=256){ int rl=idx>>9, h=idx&511; xs[rl*516+h] = X[(size_t)(r0+rl)*NH + h]; }
  __syncthreads();
  int b16 = tid & 15, cg = tid >> 4;
  int row = r0 + b16;
  int srow = row >> 5, brow = row & 31;
  int tg = tgt[brow*NS + srow];
  int cap = tg < C1V ? tg : (C1V-1);
  float lsum = 0.f;
  const float4* x4 = (const float4*)(xs + b16*516);
  for (int kk0 = 0; kk0 < 16; kk0 += 8){
    float acc[8];
    const float4* wp[8];
    #pragma unroll
    for (int j=0;j<8;j++){
      acc[j] = 0.f;
      int c = c0 + cg + (kk0+j)*16;
      wp[j] = (const float4*)(hw + (size_t)(c < cend ? c : c0)*NH);
    }
    #pragma unroll 2
    for (int h=0; h<128; h++){
      float4 xx = x4[h];
      #pragma unroll
      for (int j=0;j<8;j++){
        float4 ww = wp[j][h];
        acc[j] = fmaf(xx.x, ww.x, acc[j]); acc[j] = fmaf(xx.y, ww.y, acc[j]);
        acc[j] = fmaf(xx.z, ww.z, acc[j]); acc[j] = fmaf(xx.w, ww.w, acc[j]);
      }
    }
    #pragma unroll
    for (int j=0;j<8;j++){
      int c = c0 + cg + (kk0+j)*16;
      if (c < cend){
        float v = acc[j];
        lsum += __expf(v);
        if (c == cap) hlt[row] = v;
        else if (c == C1V) hc1[row] = v;
        else if (c == C1V+1) hc2[row] = v;
      }
    }
  }
  red[tid] = lsum;
  __syncthreads();
  if (tid < 16){
    float s2 = 0.f;
    for (int g=0; g<16; g++) s2 += red[g*16 + tid];
    atomicAdd(&sums[r0 + tid], s2);
  }
}

__global__ __launch_bounds__(256) void ktail1(const float* __restrict__ P1,
                                              const float* __restrict__ w2t,
                                              const int* __restrict__ tgt,
                                              float* __restrict__ sums, float* __restrict__ l1p){
  __shared__ int rlist[16];
  __shared__ float rsum[16];
  __shared__ int rcnt;
  int r0 = blockIdx.x*16, tid = threadIdx.x;
  if (tid == 0) rcnt = 0;
  __syncthreads();
  if (tid < 16){
    rsum[tid] = 0.f;
    int row = r0 + tid;
    int tg = tgt[(row&31)*NS + (row>>5)];
    if (tg >= C1V && tg < C2V){
      int i = atomicAdd(&rcnt, 1);
      rlist[i] = (tid << 16) | (tg - C1V);
    }
  }
  __syncthreads();
  int m = rcnt;
  if (m == 0) return;
  int rl = tid & 15, cg = tid >> 4;
  if (rl < m){
    int pkd = rlist[rl];
    int lrow = pkd >> 16, tl = pkd & 0xffff;
    int orow = r0 + lrow;
    float4 pr[32];
    const float4* p4 = (const float4*)(P1 + (size_t)orow*128);
    #pragma unroll
    for (int h=0;h<32;h++) pr[h] = p4[h];
    int c0 = blockIdx.y*750, cend = min(CSZ1V, c0+750);
    float lsum = 0.f;
    for (int c = c0 + cg; c < cend; c += 16){
      const float4* w4 = (const float4*)(w2t + (size_t)c*128);
      float a0=0.f,a1=0.f,a2=0.f,a3=0.f;
      #pragma unroll
      for (int h=0;h<32;h++){
        float4 ww = w4[h];
        a0=fmaf(pr[h].x,ww.x,a0); a1=fmaf(pr[h].y,ww.y,a1);
        a2=fmaf(pr[h].z,ww.z,a2); a3=fmaf(pr[h].w,ww.w,a3);
      }
      float v = (a0+a1)+(a2+a3);
      lsum += __expf(v);
      if (c == tl) l1p[orow] = v;
    }
    atomicAdd(&rsum[lrow], lsum);
  }
  __syncthreads();
  if (tid < 16 && rsum[tid] != 0.f) atomicAdd(&sums[2048 + r0 + tid], rsum[tid]);
}

__global__ __launch_bounds__(256) void ktail2(const float* __restrict__ P2,
                                              const float* __restrict__ w2t,
                                              const int* __restrict__ tgt,
                                              float* __restrict__ sums, float* __restrict__ l2p){
  __shared__ int rlist[16];
  __shared__ float rsum[16];
  __shared__ int rcnt;
  int r0 = blockIdx.x*16, tid = threadIdx.x;
  if (tid == 0) rcnt = 0;
  __syncthreads();
  if (tid < 16){
    rsum[tid] = 0.f;
    int row = r0 + tid;
    int tg = tgt[(row&31)*NS + (row>>5)];
    if (tg >= C2V){
      int i = atomicAdd(&rcnt, 1);
      rlist[i] = (tid << 16) | (tg - C2V);
    }
  }
  __syncthreads();
  int m = rcnt;
  if (m == 0) return;
  int rl = tid & 15, cg = tid >> 4;
  if (rl < m){
    int pkd = rlist[rl];
    int lrow = pkd >> 16, tl = pkd & 0xffff;
    int orow = r0 + lrow;
    float4 pr[8];
    const float4* p4 = (const float4*)(P2 + (size_t)orow*32);
    #pragma unroll
    for (int h=0;h<8;h++) pr[h] = p4[h];
    int c0 = blockIdx.y*2500, cend = min(CSZ2V, c0+2500);
    float lsum = 0.f;
    for (int c = c0 + cg; c < cend; c += 16){
      const float4* w4 = (const float4*)(w2t + (size_t)c*32);
      float a0=0.f,a1=0.f,a2=0.f,a3=0.f;
      #pragma unroll
      for (int h=0;h<8;h++){
        float4 ww = w4[h];
        a0=fmaf(pr[h].x,ww.x,a0); a1=fmaf(pr[h].y,ww.y,a1);
        a2=fmaf(pr[h].z,ww.z,a2); a3=fmaf(pr[h].w,ww.w,a3);
      }
      float v = (a0+a1)+(a2+a3);
      lsum += __expf(v);
      if (c == tl) l2p[orow] = v;
    }
    atomicAdd(&rsum[lrow], lsum);
  }
  __syncthreads();
  if (tid < 16 && rsum[tid] != 0.f) atomicAdd(&sums[4096 + r0 + tid], rsum[tid]);
}

__global__ __launch_bounds__(256) void kfinal(const float* __restrict__ sums,
                                              const float* __restrict__ hlt, const float* __restrict__ hc1,
                                              const float* __restrict__ hc2, const float* __restrict__ l1p,
                                              const float* __restrict__ l2p, const int* __restrict__ tgt,
                                              float* __restrict__ out){
  __shared__ float red[256];
  int tid = threadIdx.x;
  float acc = 0.f;
  for (int n = tid; n < 2048; n += 256){
    int s = n >> 5, b = n & 31;
    int tg = tgt[b*NS + s];
    float lsh = logf(sums[n]);
    float v;
    if (tg < C1V) v = hlt[n] - lsh;
    else if (tg < C2V) v = (hc1[n] - lsh) + (l1p[n] - logf(sums[2048+n]));
    else v = (hc2[n] - lsh) + (l2p[n] - logf(sums[4096+n]));
    out[O_LP + n] = v;
    acc += v;
  }
  red[tid] = acc;
  __syncthreads();
  for (int off=128; off>0; off>>=1){ if (tid<off) red[tid] += red[tid+off]; __syncthreads(); }
  if (tid==0) out[O_LOSS] = -red[0] / 2048.0f;
}

extern "C" void kernel_launch(void* const* d_in, const int* in_sizes, int n_in,
                              void* d_out, int out_size, void* d_ws, size_t ws_size,
                              hipStream_t stream){
  (void)in_sizes; (void)n_in; (void)out_size; (void)ws_size;
  ScanArgs sa;
  sa.inputs = (const int*)d_in[0];
  sa.topics = (const int*)d_in[1];
  sa.out0   = (const float*)d_in[2];
  sa.h0in   = (const float*)d_in[3];
  sa.c0in   = (const float*)d_in[4];
  sa.mask   = (const float*)d_in[5];
  sa.cover  = (const float*)d_in[7];
  sa.emb    = (const float*)d_in[8];
  sa.Uf     = (const float*)d_in[9];
  sa.Ua     = (const float*)d_in[10];
  sa.Wa     = (const float*)d_in[11];
  sa.vaw    = (const float*)d_in[12];
  sa.vab    = (const float*)d_in[13];
  sa.wih0   = (const float*)d_in[14];
  sa.whh0   = (const float*)d_in[15];
  sa.bih0   = (const float*)d_in[16];
  sa.bhh0   = (const float*)d_in[17];
  sa.wih1   = (const float*)d_in[18];
  sa.whh1   = (const float*)d_in[19];
  sa.bih1   = (const float*)d_in[20];
  sa.bhh1   = (const float*)d_in[21];
  sa.ws  = (char*)d_ws;
  sa.out = (float*)d_out;

  char* wsb = (char*)d_ws;
  const int* target = (const int*)d_in[6];
  float* outf = (float*)d_out;

  hipMemsetAsync(wsb + SUMS_B, 0, 6144*sizeof(float), stream);
  hipMemsetAsync(wsb + BAR_B, 0, 16384, stream);   // barrier flags + go

  static int lds_set = 0;
  if (!lds_set){
    hipFuncSetAttribute((const void*)scan_kernel,
                        hipFuncAttributeMaxDynamicSharedMemorySize, LDS_BYTES);
    lds_set = 1;
  }

  void* args[] = { (void*)&sa };
  hipLaunchCooperativeKernel((void*)scan_kernel, dim3(208), dim3(256), args, LDS_BYTES, stream);

  const float* X = outf + O_OUTS;
  kproj<<<dim3(128),dim3(256),0,stream>>>(X, (const float*)d_in[23], (const float*)d_in[25],
                                          (float*)(wsb+P1_B), (float*)(wsb+P2_B));
  khead<<<dim3(128,10),dim3(256),0,stream>>>(X, (const float*)d_in[22], target,
           (float*)(wsb+SUMS_B), (float*)(wsb+HLT_B), (float*)(wsb+HC1_B), (float*)(wsb+HC2_B));
  ktail1<<<dim3(128,10),dim3(256),0,stream>>>((const float*)(wsb+P1_B), (const float*)d_in[24], target,
           (float*)(wsb+SUMS_B), (float*)(wsb+L1P_B));
  ktail2<<<dim3(128,16),dim3(256),0,stream>>>((const float*)(wsb+P2_B), (const float*)d_in[26], target,
           (float*)(wsb+SUMS_B), (float*)(wsb+L2P_B));
  kfinal<<<dim3(1),dim3(256),0,stream>>>((const float*)(wsb+SUMS_B),
           (const float*)(wsb+HLT_B), (const float*)(wsb+HC1_B), (const float*)(wsb+HC2_B),
           (const float*)(wsb+L1P_B), (const float*)(wsb+L2P_B), target, outf);
}